// Round 2
// baseline (299.134 us; speedup 1.0000x reference)
//
#include <hip/hip_runtime.h>
#include <hip/hip_bf16.h>
#include <stdint.h>
#include <stddef.h>

#define HH_EPS 1e-8f

typedef __attribute__((ext_vector_type(8))) short short8;
typedef __attribute__((ext_vector_type(4))) float f32x4;

// ---------------------------------------------------------------------------
// Kernel 1: W = H_32 ... H_1 with on-the-fly normalization.
// Column j evolves independently:  w <- w - 2 (v.w)/(|v|+eps)^2 v.
// One wave per 2 columns (two independent dep chains + the |v|^2 reduce all
// ride the same 6-step shuffle ladder -> 3x the ILP of round 1's version).
// Output: W bf16 row-major [o][c] (GEMM A operand).  64 blocks x 256 threads.
// ---------------------------------------------------------------------------
__global__ void compute_w(const float* __restrict__ V,
                          __hip_bfloat16* __restrict__ Wb) {
    const int wave = threadIdx.x >> 6;
    const int lane = threadIdx.x & 63;
    const int jA = (blockIdx.x * 4 + wave) * 2;   // columns jA, jA+1
    const int jB = jA + 1;
    const int ib = lane * 8;                      // rows ib..ib+7 in this lane

    float wA[8], wB[8];
    #pragma unroll
    for (int r = 0; r < 8; r++) {
        wA[r] = (ib + r == jA) ? 1.0f : 0.0f;
        wB[r] = (ib + r == jB) ? 1.0f : 0.0f;
    }

    // prefetch v row 0
    float4 c0 = *(const float4*)(V + ib);
    float4 c1 = *(const float4*)(V + ib + 4);

    for (int k = 0; k < 32; k++) {
        const float v[8] = {c0.x, c0.y, c0.z, c0.w, c1.x, c1.y, c1.z, c1.w};
        if (k < 31) {   // issue next row's loads before the latency chain
            c0 = *(const float4*)(V + (size_t)(k + 1) * 512 + ib);
            c1 = *(const float4*)(V + (size_t)(k + 1) * 512 + ib + 4);
        }
        float dA = 0.0f, dB = 0.0f, ss = 0.0f;
        #pragma unroll
        for (int r = 0; r < 8; r++) {
            dA += v[r] * wA[r];
            dB += v[r] * wB[r];
            ss += v[r] * v[r];
        }
        #pragma unroll
        for (int off = 32; off > 0; off >>= 1) {
            dA += __shfl_xor(dA, off);
            dB += __shfl_xor(dB, off);
            ss += __shfl_xor(ss, off);
        }
        const float t = sqrtf(ss) + HH_EPS;
        const float scale = 2.0f / (t * t);       // w -= 2 (v.w)/(|v|+eps)^2 v
        const float tA = scale * dA, tB = scale * dB;
        #pragma unroll
        for (int r = 0; r < 8; r++) {
            wA[r] -= tA * v[r];
            wB[r] -= tB * v[r];
        }
    }
    #pragma unroll
    for (int r = 0; r < 8; r++) {
        Wb[(size_t)(ib + r) * 512 + jA] = __float2bfloat16(wA[r]);
        Wb[(size_t)(ib + r) * 512 + jB] = __float2bfloat16(wB[r]);
    }
}

// ---------------------------------------------------------------------------
// Kernel 2: out[b] = W @ x[b].  M=512 (o), K=512 (c), N=4096 (hw), 16 batches.
// 128x128 tile, BK=32, 256 threads = 4 waves 2x2, each wave 4x4 MFMA
// 16x16x32 bf16.  Double-buffered LDS, register prefetch, 1 barrier/k-step:
//   issue global loads(kt+1) -> read frags(kt) -> MFMA(kt) -> cvt+write
//   LDS(kt+1) -> barrier.  The vmcnt wait on the prefetch lands after the
//   MFMA block instead of immediately after issue.
// Grid swizzle: flat = mt*512 + (b*32+nt), so the 4 m-tile blocks sharing an
// x-stripe differ by 512 = 0 mod 8 -> same XCD -> L2 serves the x re-reads.
// ---------------------------------------------------------------------------
#define BM 128
#define BN 128
#define BK 32
#define CDIM 512
#define SDIM 4096
#define BROW 40   // padded Blds row stride in bf16 (32 + 8)

__device__ __forceinline__ void issue_loads(
    const float* __restrict__ xb, const __hip_bfloat16* __restrict__ Wb,
    int k0, int m0, int n0, int tid, short8 a_pf[2], float b_pf[16])
{
    #pragma unroll
    for (int c = 0; c < 2; c++) {   // A: W[m0..+127][k0..+31], 2 x 16B / thread
        const int chunk = c * 256 + tid;
        const int row = chunk >> 2, seg = chunk & 3;
        a_pf[c] = *(const short8*)(Wb + (size_t)(m0 + row) * CDIM + k0 + seg * 8);
    }
    #pragma unroll
    for (int c = 0; c < 2; c++) {   // B: x[k0..+31][n0..+127], 8 strided fp32
        const int u = c * 256 + tid;
        const int n = u & 127, kg = u >> 7;
        const float* gp = xb + (size_t)(k0 + kg * 8) * SDIM + n0 + n;
        #pragma unroll
        for (int j = 0; j < 8; j++) b_pf[c * 8 + j] = gp[(size_t)j * SDIM];
    }
}

__device__ __forceinline__ void write_lds(
    __hip_bfloat16* __restrict__ Al, __hip_bfloat16* __restrict__ Bl,
    int tid, const short8 a_pf[2], const float b_pf[16])
{
    #pragma unroll
    for (int c = 0; c < 2; c++) {
        const int chunk = c * 256 + tid;
        *(short8*)(&Al[chunk * 8]) = a_pf[c];
    }
    #pragma unroll
    for (int c = 0; c < 2; c++) {
        const int u = c * 256 + tid;
        const int n = u & 127, kg = u >> 7;
        short8 pk;
        #pragma unroll
        for (int j = 0; j < 8; j++) {
            __hip_bfloat16 h = __float2bfloat16(b_pf[c * 8 + j]);
            pk[j] = *(short*)&h;
        }
        *(short8*)(&Bl[n * BROW + kg * 8]) = pk;
    }
}

__global__ __launch_bounds__(256, 3) void hh_gemm(
    const float* __restrict__ x,
    const __hip_bfloat16* __restrict__ Wb,
    float* __restrict__ out)
{
    __shared__ __attribute__((aligned(16))) __hip_bfloat16 Alds[2][BM * BK];
    __shared__ __attribute__((aligned(16))) __hip_bfloat16 Blds[2][BN * BROW];

    const int tid  = threadIdx.x;
    const int wave = tid >> 6, lane = tid & 63;
    const int quad = lane >> 4, l16 = lane & 15;
    const int wm = wave >> 1, wn = wave & 1;

    // XCD-locality swizzle: same (nt,b) group -> flat ids differ by 512 -> same XCD
    const int bid  = blockIdx.x;          // 0..2047
    const int mt   = bid >> 9;            // 0..3
    const int rest = bid & 511;
    const int b    = rest >> 5;           // 0..15
    const int nt   = rest & 31;           // 0..31
    const int m0 = mt * BM, n0 = nt * BN;

    const float* xb = x + (size_t)b * CDIM * SDIM;

    f32x4 acc[4][4];
    #pragma unroll
    for (int i = 0; i < 4; i++)
        #pragma unroll
        for (int jj = 0; jj < 4; jj++) {
            f32x4 z = {0.0f, 0.0f, 0.0f, 0.0f};
            acc[i][jj] = z;
        }

    short8 a_pf[2];
    float  b_pf[16];

    // prologue: tile 0 -> LDS[0]
    issue_loads(xb, Wb, 0, m0, n0, tid, a_pf, b_pf);
    write_lds(Alds[0], Blds[0], tid, a_pf, b_pf);
    __syncthreads();

    for (int kt = 0; kt < CDIM / BK; kt++) {
        const int cur = kt & 1;

        if (kt < CDIM / BK - 1)
            issue_loads(xb, Wb, (kt + 1) * BK, m0, n0, tid, a_pf, b_pf);

        short8 af[4], bfr[4];
        #pragma unroll
        for (int mi = 0; mi < 4; mi++)
            af[mi] = *(const short8*)(&Alds[cur][(wm * 64 + mi * 16 + l16) * BK + quad * 8]);
        #pragma unroll
        for (int ni = 0; ni < 4; ni++)
            bfr[ni] = *(const short8*)(&Blds[cur][(wn * 64 + ni * 16 + l16) * BROW + quad * 8]);
        #pragma unroll
        for (int mi = 0; mi < 4; mi++)
            #pragma unroll
            for (int ni = 0; ni < 4; ni++)
                acc[mi][ni] = __builtin_amdgcn_mfma_f32_16x16x32_bf16(
                    af[mi], bfr[ni], acc[mi][ni], 0, 0, 0);

        if (kt < CDIM / BK - 1)
            write_lds(Alds[cur ^ 1], Blds[cur ^ 1], tid, a_pf, b_pf);
        __syncthreads();
    }

    // epilogue: D[row][col], col = l16, row = quad*4 + r
    float* ob = out + (size_t)b * CDIM * SDIM;
    #pragma unroll
    for (int mi = 0; mi < 4; mi++) {
        #pragma unroll
        for (int ni = 0; ni < 4; ni++) {
            const int col = n0 + wn * 64 + ni * 16 + l16;
            #pragma unroll
            for (int r = 0; r < 4; r++) {
                const int row = m0 + wm * 64 + mi * 16 + quad * 4 + r;
                ob[(size_t)row * SDIM + col] = acc[mi][ni][r];
            }
        }
    }
}

// ---------------------------------------------------------------------------
extern "C" void kernel_launch(void* const* d_in, const int* in_sizes, int n_in,
                              void* d_out, int out_size, void* d_ws, size_t ws_size,
                              hipStream_t stream) {
    const float* x = (const float*)d_in[0];   // [16, 512, 64, 64]
    const float* V = (const float*)d_in[1];   // [32, 512]
    float* out = (float*)d_out;               // [16, 512, 64, 64] fp32

    __hip_bfloat16* Wb = (__hip_bfloat16*)d_ws;  // 512 KB

    compute_w<<<64, 256, 0, stream>>>(V, Wb);
    hh_gemm<<<2048, 256, 0, stream>>>(x, Wb, out);
}

// Round 3
// 284.034 us; speedup vs baseline: 1.0532x; 1.0532x over previous
//
#include <hip/hip_runtime.h>
#include <hip/hip_bf16.h>
#include <stdint.h>
#include <stddef.h>

#define HH_EPS 1e-8f

typedef __attribute__((ext_vector_type(8))) short short8;
typedef __attribute__((ext_vector_type(4))) float f32x4;

#define CDIM 512
#define SDIM 4096
#define BN 64
#define BK 32
#define NSTEP 16      // CDIM / BK
#define BROW 40       // padded B-tile row stride in bf16 (80 B = 20 banks, 16B-aligned)

// ---------------------------------------------------------------------------
// Frag-tiled W layout: for the GEMM, wave `wv` loads A-frag mi as ONE
// contiguous 1KB block.  Element (o, c) lives at:
//   kt = c>>5, m16 = o>>4, l16 = o&15, quad = (c>>3)&3, j = c&7
//   bf16 offset = ((kt*32 + m16)*64 + l16*4 + quad)*8 + j
// ---------------------------------------------------------------------------
__device__ __forceinline__ size_t wt_idx(int o, int c) {
    return ((size_t)((c >> 5) * 32 + (o >> 4)) * 64
            + (size_t)((o & 15) * 4 + ((c >> 3) & 3))) * 8 + (c & 7);
}

// ---------------------------------------------------------------------------
// Kernel 1: W = H_32 ... H_1, column-parallel, on-the-fly normalization.
// One wave per 2 columns.  Output: frag-tiled bf16 W (512 KB in ws).
// ---------------------------------------------------------------------------
__global__ void compute_w(const float* __restrict__ V,
                          __hip_bfloat16* __restrict__ Wt) {
    const int wave = threadIdx.x >> 6;
    const int lane = threadIdx.x & 63;
    const int jA = (blockIdx.x * 4 + wave) * 2;
    const int jB = jA + 1;
    const int ib = lane * 8;

    float wA[8], wB[8];
    #pragma unroll
    for (int r = 0; r < 8; r++) {
        wA[r] = (ib + r == jA) ? 1.0f : 0.0f;
        wB[r] = (ib + r == jB) ? 1.0f : 0.0f;
    }

    float4 c0 = *(const float4*)(V + ib);
    float4 c1 = *(const float4*)(V + ib + 4);

    for (int k = 0; k < 32; k++) {
        const float v[8] = {c0.x, c0.y, c0.z, c0.w, c1.x, c1.y, c1.z, c1.w};
        if (k < 31) {
            c0 = *(const float4*)(V + (size_t)(k + 1) * 512 + ib);
            c1 = *(const float4*)(V + (size_t)(k + 1) * 512 + ib + 4);
        }
        float dA = 0.0f, dB = 0.0f, ss = 0.0f;
        #pragma unroll
        for (int r = 0; r < 8; r++) {
            dA += v[r] * wA[r];
            dB += v[r] * wB[r];
            ss += v[r] * v[r];
        }
        #pragma unroll
        for (int off = 32; off > 0; off >>= 1) {
            dA += __shfl_xor(dA, off);
            dB += __shfl_xor(dB, off);
            ss += __shfl_xor(ss, off);
        }
        const float t = sqrtf(ss) + HH_EPS;
        const float scale = 2.0f / (t * t);
        const float tA = scale * dA, tB = scale * dB;
        #pragma unroll
        for (int r = 0; r < 8; r++) {
            wA[r] -= tA * v[r];
            wB[r] -= tB * v[r];
        }
    }
    #pragma unroll
    for (int r = 0; r < 8; r++) {
        Wt[wt_idx(ib + r, jA)] = __float2bfloat16(wA[r]);
        Wt[wt_idx(ib + r, jB)] = __float2bfloat16(wB[r]);
    }
}

// ---------------------------------------------------------------------------
// LDS barrier WITHOUT the vmcnt(0) drain __syncthreads forces:
// per-wave lgkmcnt(0) (all my LDS reads/writes visible) + raw s_barrier.
// Global prefetch loads stay in flight across it (AITER pattern).
// imm 0xC07F = vmcnt(63) expcnt(7) lgkmcnt(0).
// ---------------------------------------------------------------------------
__device__ __forceinline__ void lds_barrier() {
    asm volatile("" ::: "memory");
    __builtin_amdgcn_s_waitcnt(0xC07F);
    __builtin_amdgcn_s_barrier();
    asm volatile("" ::: "memory");
}

// ---------------------------------------------------------------------------
// Kernel 2: out[b] = W @ x[b].  BM=512 (ALL of M -> each x element fetched
// exactly once from HBM), BN=64, BK=32, 256 threads = 4 waves, each wave
// 128 rows x 64 cols = 8x4 MFMA 16x16x32 tiles (32 MFMA / wave / k-step).
//   A-frags: direct global_load_dwordx4 from frag-tiled W (L2-resident),
//            prefetch distance 1, no LDS.
//   B-tile : 64x32 fp32 gather -> bf16 -> LDS (double-buffered, 10 KB),
//            register prefetch distance 2; loads cross the raw s_barrier.
// ---------------------------------------------------------------------------
__global__ __launch_bounds__(256, 2) void hh_gemm(
    const float* __restrict__ x,
    const short8* __restrict__ Wt16,
    float* __restrict__ out)
{
    __shared__ __attribute__((aligned(16))) __hip_bfloat16 Blds[2][BN * BROW];

    const int tid  = threadIdx.x;
    const int wave = tid >> 6, lane = tid & 63;
    const int quad = lane >> 4, l16 = lane & 15;

    const int bid = blockIdx.x;          // 0..1023
    const int b   = bid >> 6;            // 0..15
    const int nt  = bid & 63;            // 0..63
    const int n0  = nt * BN;

    const float* xb = x + (size_t)b * CDIM * SDIM;

    // B staging ownership: thread covers n = tid&63, k-group kg = tid>>6 (8 k's)
    const int bn = tid & 63, kg = tid >> 6;
    const float* xp0 = xb + (size_t)(kg * 8) * SDIM + n0 + bn;

    f32x4 acc[8][4];
    #pragma unroll
    for (int mi = 0; mi < 8; mi++)
        #pragma unroll
        for (int ni = 0; ni < 4; ni++) {
            f32x4 z = {0.0f, 0.0f, 0.0f, 0.0f};
            acc[mi][ni] = z;
        }

    short8 af[2][8];      // A frags, double-buffered by k-step parity
    float  pfB[2][8];     // B stage regs, distance-2 prefetch

    auto loadB = [&](int kt, float* dst) {
        const float* p = xp0 + (size_t)kt * BK * SDIM;
        #pragma unroll
        for (int j = 0; j < 8; j++) dst[j] = p[(size_t)j * SDIM];
    };
    auto writeB = [&](int buf, const float* src) {
        short8 pk;
        #pragma unroll
        for (int j = 0; j < 8; j++) {
            __hip_bfloat16 h = __float2bfloat16(src[j]);
            pk[j] = *(short*)&h;
        }
        *(short8*)(&Blds[buf][bn * BROW + kg * 8]) = pk;
    };
    auto loadA = [&](int kt, short8* dst) {
        const short8* p = Wt16 + (size_t)kt * 2048 + (size_t)(wave * 8) * 64
                        + l16 * 4 + quad;
        #pragma unroll
        for (int mi = 0; mi < 8; mi++) dst[mi] = p[mi * 64];
    };

    // prologue: B0, B1 in regs; A0 in regs; B0 -> LDS[0]
    loadB(0, pfB[0]);
    loadB(1, pfB[1]);
    loadA(0, af[0]);
    writeB(0, pfB[0]);
    lds_barrier();

    auto step = [&](int kt, int p, bool pfb, bool pfa, bool last) {
        if (pfb) loadB(kt + 2, pfB[p]);       // consumed at step kt+1's tail
        if (pfa) loadA(kt + 1, af[p ^ 1]);
        short8 bfr[4];
        #pragma unroll
        for (int ni = 0; ni < 4; ni++)
            bfr[ni] = *(const short8*)(&Blds[p][(ni * 16 + l16) * BROW + quad * 8]);
        #pragma unroll
        for (int mi = 0; mi < 8; mi++)
            #pragma unroll
            for (int ni = 0; ni < 4; ni++)
                acc[mi][ni] = __builtin_amdgcn_mfma_f32_16x16x32_bf16(
                    af[p][mi], bfr[ni], acc[mi][ni], 0, 0, 0);
        if (!last) {
            writeB(p ^ 1, pfB[p ^ 1]);        // B(kt+1): loads 2 steps old
            lds_barrier();
        }
    };

    for (int kt = 0; kt < NSTEP - 2; kt += 2) {   // kt = 0..13
        step(kt,     0, true, true, false);
        step(kt + 1, 1, true, true, false);
    }
    step(NSTEP - 2, 0, false, true,  false);      // kt=14: no B prefetch
    step(NSTEP - 1, 1, false, false, true);       // kt=15: compute only

    // epilogue: D col = l16, row = quad*4 + r
    float* ob = out + (size_t)b * CDIM * SDIM + n0;
    #pragma unroll
    for (int mi = 0; mi < 8; mi++) {
        #pragma unroll
        for (int ni = 0; ni < 4; ni++) {
            const int col = ni * 16 + l16;
            #pragma unroll
            for (int r = 0; r < 4; r++) {
                const int row = wave * 128 + mi * 16 + quad * 4 + r;
                ob[(size_t)row * SDIM + col] = acc[mi][ni][r];
            }
        }
    }
}

// ---------------------------------------------------------------------------
extern "C" void kernel_launch(void* const* d_in, const int* in_sizes, int n_in,
                              void* d_out, int out_size, void* d_ws, size_t ws_size,
                              hipStream_t stream) {
    const float* x = (const float*)d_in[0];   // [16, 512, 64, 64]
    const float* V = (const float*)d_in[1];   // [32, 512]
    float* out = (float*)d_out;               // [16, 512, 64, 64] fp32

    __hip_bfloat16* Wt = (__hip_bfloat16*)d_ws;   // 512 KB frag-tiled W

    compute_w<<<64, 256, 0, stream>>>(V, Wt);
    hh_gemm<<<1024, 256, 0, stream>>>(x, (const short8*)Wt, out);
}

// Round 4
// 273.652 us; speedup vs baseline: 1.0931x; 1.0379x over previous
//
#include <hip/hip_runtime.h>
#include <hip/hip_bf16.h>
#include <stdint.h>
#include <stddef.h>

#define HH_EPS 1e-8f

typedef __attribute__((ext_vector_type(8))) short short8;
typedef __attribute__((ext_vector_type(4))) float f32x4;

#define CDIM 512
#define SDIM 4096
#define BN 64
#define BK 32
#define NSTEP 16      // CDIM / BK
#define BROW 40       // padded B-tile row stride in bf16 (80 B, 16B-aligned)

// ---------------------------------------------------------------------------
// Frag-tiled W: element (o,c) at ((c>>5)*32 + (o>>4))*512 + ((o&15)*4 + ((c>>3)&3))*8 + (c&7).
// Per k-tile, per 16-row group: 1024 contiguous bytes in exact lane-consume
// order -> global_load_lds-able and ds_read_b128-able with zero repacking.
// ---------------------------------------------------------------------------
__device__ __forceinline__ size_t wt_idx(int o, int c) {
    return ((size_t)((c >> 5) * 32 + (o >> 4)) * 64
            + (size_t)((o & 15) * 4 + ((c >> 3) & 3))) * 8 + (c & 7);
}

// ---------------------------------------------------------------------------
// Kernel 1: W = H_32 ... H_1, column-parallel, on-the-fly normalization.
// ---------------------------------------------------------------------------
__global__ void compute_w(const float* __restrict__ V,
                          __hip_bfloat16* __restrict__ Wt) {
    const int wave = threadIdx.x >> 6;
    const int lane = threadIdx.x & 63;
    const int jA = (blockIdx.x * 4 + wave) * 2;
    const int jB = jA + 1;
    const int ib = lane * 8;

    float wA[8], wB[8];
    #pragma unroll
    for (int r = 0; r < 8; r++) {
        wA[r] = (ib + r == jA) ? 1.0f : 0.0f;
        wB[r] = (ib + r == jB) ? 1.0f : 0.0f;
    }
    float4 c0 = *(const float4*)(V + ib);
    float4 c1 = *(const float4*)(V + ib + 4);

    for (int k = 0; k < 32; k++) {
        const float v[8] = {c0.x, c0.y, c0.z, c0.w, c1.x, c1.y, c1.z, c1.w};
        if (k < 31) {
            c0 = *(const float4*)(V + (size_t)(k + 1) * 512 + ib);
            c1 = *(const float4*)(V + (size_t)(k + 1) * 512 + ib + 4);
        }
        float dA = 0.0f, dB = 0.0f, ss = 0.0f;
        #pragma unroll
        for (int r = 0; r < 8; r++) {
            dA += v[r] * wA[r];
            dB += v[r] * wB[r];
            ss += v[r] * v[r];
        }
        #pragma unroll
        for (int off = 32; off > 0; off >>= 1) {
            dA += __shfl_xor(dA, off);
            dB += __shfl_xor(dB, off);
            ss += __shfl_xor(ss, off);
        }
        const float t = sqrtf(ss) + HH_EPS;
        const float scale = 2.0f / (t * t);
        const float tA = scale * dA, tB = scale * dB;
        #pragma unroll
        for (int r = 0; r < 8; r++) {
            wA[r] -= tA * v[r];
            wB[r] -= tB * v[r];
        }
    }
    #pragma unroll
    for (int r = 0; r < 8; r++) {
        Wt[wt_idx(ib + r, jA)] = __float2bfloat16(wA[r]);
        Wt[wt_idx(ib + r, jB)] = __float2bfloat16(wB[r]);
    }
}

// ---------------------------------------------------------------------------
// Async / sync primitives
// ---------------------------------------------------------------------------
__device__ __forceinline__ void gld_lds16(const void* g, void* l) {
    __builtin_amdgcn_global_load_lds(
        (const __attribute__((address_space(1))) uint32_t*)g,
        (__attribute__((address_space(3))) uint32_t*)l, 16, 0, 0);
}

template<int N> __device__ __forceinline__ void wait_vm() {
    // gfx9 s_waitcnt imm: vmcnt[3:0]=b3:0, vmcnt[5:4]=b15:14, exp=b6:4, lgkm=b11:8
    __builtin_amdgcn_s_waitcnt((N & 15) | ((N >> 4) << 14) | (7 << 4) | (15 << 8));
}

__device__ __forceinline__ void lds_barrier() {
    // lgkmcnt(0) only: my LDS ops visible; global loads stay in flight.
    __builtin_amdgcn_s_waitcnt(0xC07F);
    __builtin_amdgcn_s_barrier();
}

// # of loads issued AFTER A(kt) at the manual wait point of step kt:
// A(kt+1) [this step], B(kt+2) [prev step, after A(kt)], B(kt+3) [this step]
constexpr int vm_after_A(int kt) {
    int n = 0;
    if (kt + 1 < NSTEP) n += 8;
    if (kt + 2 < NSTEP) n += 8;
    if (kt + 3 < NSTEP) n += 8;
    return n;
}

// ---------------------------------------------------------------------------
// Kernel 2: out[b] = W @ x[b].  BM=512 (all of M -> x fetched once), BN=64,
// BK=32, 256 thr / 4 waves, wave = 128 rows x 64 cols = 8x4 MFMA/step.
//   A: global_load_lds (no VGPR round-trip), wave-private LDS dbuf, dist-1.
//   B: fp32 gather -> 3-deep reg stages (dist-3) -> cvt -> LDS dbuf.
//   Sync: manual vmcnt(24/16/8/0) + lgkm-only raw barrier -> B prefetch and
//   A(kt+1) DMA stay in flight across the barrier (AITER pattern).
// ---------------------------------------------------------------------------
__global__ __launch_bounds__(256, 2) void hh_gemm(
    const float* __restrict__ x,
    const __hip_bfloat16* __restrict__ Wt,
    float* __restrict__ out)
{
    __shared__ __attribute__((aligned(16))) __hip_bfloat16 Albuf[2][512 * BK]; // 2 x 32 KB
    __shared__ __attribute__((aligned(16))) __hip_bfloat16 Bbuf[2][BN * BROW]; // 2 x 5 KB

    const int tid  = threadIdx.x;
    const int wave = tid >> 6, lane = tid & 63;
    const int quad = lane >> 4, l16 = lane & 15;

    const int bid = blockIdx.x;          // 0..1023
    const int b   = bid >> 6;            // 0..15
    const int nt  = bid & 63;            // 0..63
    const int n0  = nt * BN;

    const float* xb = x + (size_t)b * CDIM * SDIM;
    const int bn = tid & 63;             // n owned for B staging
    const float* xp0 = xb + (size_t)(wave * 8) * SDIM + n0 + bn;  // kg == wave

    f32x4 acc[8][4];
    #pragma unroll
    for (int mi = 0; mi < 8; mi++)
        #pragma unroll
        for (int ni = 0; ni < 4; ni++) {
            f32x4 z = {0.0f, 0.0f, 0.0f, 0.0f};
            acc[mi][ni] = z;
        }

    float pfB[3][8];

    auto loadA = [&](int kt, int p) {   // 8 x (64 lanes x 16 B) wave-private bursts
        const char* gbase = (const char*)Wt
            + ((size_t)kt * 32 + (size_t)wave * 8) * 1024 + (size_t)lane * 16;
        char* lbase = (char*)&Albuf[p][(size_t)(wave * 8) * 512];
        #pragma unroll
        for (int i = 0; i < 8; i++)
            gld_lds16(gbase + (size_t)i * 1024, lbase + (size_t)i * 1024);
    };
    auto loadB = [&](int kt, float* dst) {
        const float* p = xp0 + (size_t)kt * BK * SDIM;
        #pragma unroll
        for (int j = 0; j < 8; j++) dst[j] = p[(size_t)j * SDIM];
    };
    auto writeB = [&](int buf, const float* src) {
        short8 pk;
        #pragma unroll
        for (int j = 0; j < 8; j++) {
            __hip_bfloat16 h = __float2bfloat16(src[j]);
            pk[j] = *(short*)&h;
        }
        *(short8*)(&Bbuf[buf][bn * BROW + wave * 8]) = pk;
    };

    // ---- prologue: A(0)->LDS0, B(0..2)->regs, B(0)->LDS0 ----
    loadA(0, 0);
    loadB(0, pfB[0]);
    loadB(1, pfB[1]);
    loadB(2, pfB[2]);
    writeB(0, pfB[0]);    // compiler vmcnt wait retires A(0),B(0); B(1),B(2) fly
    lds_barrier();

#define DO_STEP(KT)                                                            \
    {                                                                          \
        constexpr int p = (KT) & 1;                                            \
        if constexpr ((KT) + 1 < NSTEP) loadA((KT) + 1, p ^ 1);                \
        if constexpr ((KT) + 3 < NSTEP) loadB((KT) + 3, pfB[(KT) % 3]);        \
        wait_vm<vm_after_A(KT)>();  /* A(kt) landed; young loads in flight */  \
        short8 afr[8], bfr[4];                                                 \
        _Pragma("unroll")                                                      \
        for (int mi = 0; mi < 8; mi++)                                         \
            afr[mi] = *(const short8*)(&Albuf[p][(wave * 8 + mi) * 512         \
                                                 + (l16 * 4 + quad) * 8]);     \
        _Pragma("unroll")                                                      \
        for (int ni = 0; ni < 4; ni++)                                         \
            bfr[ni] = *(const short8*)(&Bbuf[p][(ni * 16 + l16) * BROW         \
                                                + quad * 8]);                  \
        _Pragma("unroll")                                                      \
        for (int mi = 0; mi < 8; mi++)                                         \
            _Pragma("unroll")                                                  \
            for (int ni = 0; ni < 4; ni++)                                     \
                acc[mi][ni] = __builtin_amdgcn_mfma_f32_16x16x32_bf16(         \
                    afr[mi], bfr[ni], acc[mi][ni], 0, 0, 0);                   \
        if constexpr ((KT) + 1 < NSTEP) {                                      \
            writeB(p ^ 1, pfB[((KT) + 1) % 3]);                                \
            lds_barrier();                                                     \
        }                                                                      \
    }

    DO_STEP(0)  DO_STEP(1)  DO_STEP(2)  DO_STEP(3)
    DO_STEP(4)  DO_STEP(5)  DO_STEP(6)  DO_STEP(7)
    DO_STEP(8)  DO_STEP(9)  DO_STEP(10) DO_STEP(11)
    DO_STEP(12) DO_STEP(13) DO_STEP(14) DO_STEP(15)
#undef DO_STEP

    // ---- epilogue: D col = l16, row = quad*4 + r ----
    float* ob = out + (size_t)b * CDIM * SDIM + n0;
    #pragma unroll
    for (int mi = 0; mi < 8; mi++) {
        #pragma unroll
        for (int ni = 0; ni < 4; ni++) {
            const int col = ni * 16 + l16;
            #pragma unroll
            for (int r = 0; r < 4; r++) {
                const int row = wave * 128 + mi * 16 + quad * 4 + r;
                ob[(size_t)row * SDIM + col] = acc[mi][ni][r];
            }
        }
    }
}

// ---------------------------------------------------------------------------
extern "C" void kernel_launch(void* const* d_in, const int* in_sizes, int n_in,
                              void* d_out, int out_size, void* d_ws, size_t ws_size,
                              hipStream_t stream) {
    const float* x = (const float*)d_in[0];   // [16, 512, 64, 64]
    const float* V = (const float*)d_in[1];   // [32, 512]
    float* out = (float*)d_out;               // [16, 512, 64, 64] fp32

    __hip_bfloat16* Wt = (__hip_bfloat16*)d_ws;   // 512 KB frag-tiled W

    compute_w<<<64, 256, 0, stream>>>(V, Wt);
    hh_gemm<<<1024, 256, 0, stream>>>(x, Wt, out);
}